// Round 6
// baseline (393.454 us; speedup 1.0000x reference)
//
#include <hip/hip_runtime.h>
#include <math.h>

// Shapes fixed by the reference: B=4, N=4096, H=16, D=64; children = 2N.
#define BB 4
#define NN 4096
#define HH 16
#define DD 64
#define ROWS (BB * NN * HH)          // 262144 (b,n,h) rows
#define OUT_ELEMS ((size_t)ROWS * DD)
#define G 2                          // rows per 16-lane group
#define GROUPS (ROWS / G)            // 131072 groups
#define BLOCK 256

typedef float f4 __attribute__((ext_vector_type(4)));

// DPP row_ror 16-lane butterfly sum (result in all 16 lanes). Pure VALU.
template <int CTRL>
__device__ __forceinline__ float row_ror_add(float v) {
    int s = __builtin_amdgcn_update_dpp(0, __float_as_int(v), CTRL, 0xf, 0xf, true);
    return v + __int_as_float(s);
}
__device__ __forceinline__ float sum16(float v) {
    v = row_ror_add<0x128>(v);   // ror 8
    v = row_ror_add<0x124>(v);   // ror 4
    v = row_ror_add<0x122>(v);   // ror 2
    v = row_ror_add<0x121>(v);   // ror 1
    return v;
}
__device__ __forceinline__ float dot4(f4 a, f4 b) {
    return a.x*b.x + a.y*b.y + a.z*b.z + a.w*b.w;
}

// Forced-MLP load. Rounds 0/2/5 proved the compiler serializes ntload to
// ~5 outstanding/wave no matter what (VGPR_Count 32 even with a
// sched_barrier pin — round 5). Volatile asm loads cannot be sunk,
// reordered, or rematerialized; RA must keep all 14 results live.
// NT flag PROTECTED: round-1 A/B showed the L1-allocating path costs 1.5x.
__device__ __forceinline__ f4 aload(const float* base, int byteoff) {
    f4 d;
    asm volatile("global_load_dwordx4 %0, %1, %2 nt"
                 : "=v"(d) : "v"(byteoff), "s"(base));
    return d;
}

// One 16-lane group handles rows {gid, gid+GROUPS}. All 14 loads issue
// back-to-back (QK first, V last), then each consumption phase waits with a
// hand-counted vmcnt whose asm TIES the values consumed in that phase
// ("+v" operands): true register deps that no scheduler pass can break
// (round 5 proved sched_barrier alone is not honored by this toolchain).
// Counting safety: all stores depend on post-wait data, so every other
// VMEM op issues after all 14 loads => vmcnt(N) retires >= 14-N loads.
__global__ __launch_bounds__(BLOCK) void hsa3_kernel(
    const float* __restrict__ Qp, const float* __restrict__ Kp,
    const float* __restrict__ Vp, const float* __restrict__ Kc,
    const float* __restrict__ Vc, float* __restrict__ out,
    float* __restrict__ wout)
{
    const int tid = blockIdx.x * BLOCK + threadIdx.x;
    const int gid = tid >> 4;
    const int l   = tid & 15;

    const int r0 = gid;
    const int r1 = gid + GROUPS;

    // element offsets
    const int po0e = (r0 << 6) + (l << 2);
    const int po1e = (r1 << 6) + (l << 2);
    const int cb0 = ((r0 >> 4) << 5) + (r0 & 15);
    const int cb1 = ((r1 >> 4) << 5) + (r1 & 15);
    const int c00e = (cb0 << 6) + (l << 2);
    const int c01e = (cb1 << 6) + (l << 2);
    // byte offsets
    const int po0 = po0e << 2;
    const int po1 = po1e << 2;
    const int c00 = c00e << 2;
    const int c10 = c00 + (HH << 8);
    const int c01 = c01e << 2;
    const int c11 = c01 + (HH << 8);

    // ---- issue all 14 loads in consumption order ----
    f4 q0   = aload(Qp, po0);
    f4 kp0  = aload(Kp, po0);
    f4 kc00 = aload(Kc, c00);
    f4 kc10 = aload(Kc, c10);
    f4 q1   = aload(Qp, po1);
    f4 kp1  = aload(Kp, po1);
    f4 kc01 = aload(Kc, c01);
    f4 kc11 = aload(Kc, c11);
    f4 vp0  = aload(Vp, po0);
    f4 vc00 = aload(Vc, c00);
    f4 vc10 = aload(Vc, c10);
    f4 vp1  = aload(Vp, po1);
    f4 vc01 = aload(Vc, c01);
    f4 vc11 = aload(Vc, c11);

    const float scale = 0.125f;            // 1/sqrt(64)
    const float L2E   = 1.44269504088896f; // log2(e)

    // ---- phase A: loads 1-4 done at vmcnt(10); tie q0,kp0,kc00,kc10 ----
    asm volatile("s_waitcnt vmcnt(10)"
                 : "+v"(q0), "+v"(kp0), "+v"(kc00), "+v"(kc10)
                 :: "memory");
    float dsA = sum16(dot4(q0, kp0));
    float d0A = sum16(dot4(q0, kc00));
    float d1A = sum16(dot4(q0, kc10));
    float s0 = dsA * scale, s1 = d0A * scale, s2 = d1A * scale;
    float mx = fmaxf(s0, fmaxf(s1, s2));
    float e0 = exp2f((s0 - mx) * L2E);
    float e1 = exp2f((s1 - mx) * L2E);
    float e2 = exp2f((s2 - mx) * L2E);
    float inv = __builtin_amdgcn_rcpf(e0 + e1 + e2 + 1e-9f);
    const float w0A = e0 * inv, w1A = e1 * inv, w2A = e2 * inv;

    // ---- phase B: loads 5-8 done at vmcnt(6) ----
    asm volatile("s_waitcnt vmcnt(6)"
                 : "+v"(q1), "+v"(kp1), "+v"(kc01), "+v"(kc11)
                 :: "memory");
    float dsB = sum16(dot4(q1, kp1));
    float d0B = sum16(dot4(q1, kc01));
    float d1B = sum16(dot4(q1, kc11));
    s0 = dsB * scale; s1 = d0B * scale; s2 = d1B * scale;
    mx = fmaxf(s0, fmaxf(s1, s2));
    e0 = exp2f((s0 - mx) * L2E);
    e1 = exp2f((s1 - mx) * L2E);
    e2 = exp2f((s2 - mx) * L2E);
    inv = __builtin_amdgcn_rcpf(e0 + e1 + e2 + 1e-9f);
    const float w0B = e0 * inv, w1B = e1 * inv, w2B = e2 * inv;

    // ---- phase C: loads 9-11 done at vmcnt(3) ----
    asm volatile("s_waitcnt vmcnt(3)"
                 : "+v"(vp0), "+v"(vc00), "+v"(vc10)
                 :: "memory");
    f4 oA;
    oA.x = w0A*vp0.x + w1A*vc00.x + w2A*vc10.x;
    oA.y = w0A*vp0.y + w1A*vc00.y + w2A*vc10.y;
    oA.z = w0A*vp0.z + w1A*vc00.z + w2A*vc10.z;
    oA.w = w0A*vp0.w + w1A*vc00.w + w2A*vc10.w;
    __builtin_nontemporal_store(oA, (f4*)(out + po0e));

    // ---- phase D: loads 12-14 done at vmcnt(0) (also drains oA store) ----
    asm volatile("s_waitcnt vmcnt(0)"
                 : "+v"(vp1), "+v"(vc01), "+v"(vc11)
                 :: "memory");
    f4 oB;
    oB.x = w0B*vp1.x + w1B*vc01.x + w2B*vc11.x;
    oB.y = w0B*vp1.y + w1B*vc01.y + w2B*vc11.y;
    oB.z = w0B*vp1.z + w1B*vc01.z + w2B*vc11.z;
    oB.w = w0B*vp1.w + w1B*vc01.w + w2B*vc11.w;
    __builtin_nontemporal_store(oB, (f4*)(out + po1e));

    // w output: [b,n,h,3] — lanes 0..2 store each row's weights
    if (l < 3) {
        const float wa = (l == 0) ? w0A : ((l == 1) ? w1A : w2A);
        const float wb = (l == 0) ? w0B : ((l == 1) ? w1B : w2B);
        wout[r0 * 3 + l] = wa;
        wout[r1 * 3 + l] = wb;
    }
}

extern "C" void kernel_launch(void* const* d_in, const int* in_sizes, int n_in,
                              void* d_out, int out_size, void* d_ws, size_t ws_size,
                              hipStream_t stream) {
    (void)in_sizes; (void)n_in; (void)d_ws; (void)ws_size; (void)out_size;
    const float* Qp = (const float*)d_in[0];
    const float* Kp = (const float*)d_in[1];
    const float* Vp = (const float*)d_in[2];
    const float* Kc = (const float*)d_in[3];
    const float* Vc = (const float*)d_in[4];
    float* out  = (float*)d_out;
    float* wout = out + OUT_ELEMS;    // tuple: out first, then w

    const int threads = GROUPS * 16;  // 2,097,152
    const int grid = threads / BLOCK; // 8192
    hipLaunchKernelGGL(hsa3_kernel, dim3(grid), dim3(BLOCK), 0, stream,
                       Qp, Kp, Vp, Kc, Vc, out, wout);
}